// Round 6
// baseline (172.190 us; speedup 1.0000x reference)
//
#include <hip/hip_runtime.h>
#include <math.h>

#define N_NODES 50000
#define N_EDGES 800000
#define IN_F 128
#define OUT_F 64
#define LRELU_ALPHA 0.2f

#define NPB 32                            // nodes per bucket
#define NBUCK ((N_NODES + NPB - 1) / NPB) // 1563
#define CAP 768                           // LDS chunk capacity (edges)

__device__ inline float wred_max(float v) {
#pragma unroll
    for (int o = 32; o > 0; o >>= 1) v = fmaxf(v, __shfl_down(v, o, 64));
    return v;
}
__device__ inline float wred_sum(float v) {
#pragma unroll
    for (int o = 32; o > 0; o >>= 1) v += __shfl_down(v, o, 64);
    return v;
}

// K1: Wh = x @ W, register-tiled: 64x64 tile per block, 4x4 per thread.
__global__ __launch_bounds__(256, 2) void k_wh(const float* __restrict__ x,
                                               const float* __restrict__ W,
                                               const float* __restrict__ a,
                                               float* __restrict__ Wh,
                                               float* __restrict__ sv,
                                               float* __restrict__ tv) {
    __shared__ float xs[64 * 128];  // x tile, XOR-swizzled
    __shared__ float Ws[128 * 64];  // W, natural layout

    const int tid = threadIdx.x;
    const int row0 = blockIdx.x * 64;

    for (int i = tid; i < 64 * 32; i += 256) {
        int rl = i >> 5, c4 = (i & 31) << 2;
        int r = row0 + rl;
        float4 v = make_float4(0.f, 0.f, 0.f, 0.f);
        if (r < N_NODES) v = *reinterpret_cast<const float4*>(x + (size_t)r * IN_F + c4);
        int sw = c4 ^ ((rl & 7) << 2);
        *reinterpret_cast<float4*>(&xs[rl * 128 + sw]) = v;
    }
    for (int i = tid; i < 128 * 16; i += 256) {
        int k = i >> 4, c4 = (i & 15) << 2;
        *reinterpret_cast<float4*>(&Ws[k * 64 + c4]) =
            *reinterpret_cast<const float4*>(W + k * 64 + c4);
    }
    __syncthreads();

    const int tx = tid & 15;
    const int ty = tid >> 4;
    const int c0 = tx << 2;
    const int rl0 = ty << 2;

    float acc[4][4] = {};
#pragma unroll 4
    for (int k = 0; k < 128; ++k) {
        float4 b = *reinterpret_cast<const float4*>(&Ws[k * 64 + c0]);
        float a0 = xs[(rl0 + 0) * 128 + (k ^ (((rl0 + 0) & 7) << 2))];
        float a1 = xs[(rl0 + 1) * 128 + (k ^ (((rl0 + 1) & 7) << 2))];
        float a2 = xs[(rl0 + 2) * 128 + (k ^ (((rl0 + 2) & 7) << 2))];
        float a3 = xs[(rl0 + 3) * 128 + (k ^ (((rl0 + 3) & 7) << 2))];
        acc[0][0] = fmaf(a0, b.x, acc[0][0]);
        acc[0][1] = fmaf(a0, b.y, acc[0][1]);
        acc[0][2] = fmaf(a0, b.z, acc[0][2]);
        acc[0][3] = fmaf(a0, b.w, acc[0][3]);
        acc[1][0] = fmaf(a1, b.x, acc[1][0]);
        acc[1][1] = fmaf(a1, b.y, acc[1][1]);
        acc[1][2] = fmaf(a1, b.z, acc[1][2]);
        acc[1][3] = fmaf(a1, b.w, acc[1][3]);
        acc[2][0] = fmaf(a2, b.x, acc[2][0]);
        acc[2][1] = fmaf(a2, b.y, acc[2][1]);
        acc[2][2] = fmaf(a2, b.z, acc[2][2]);
        acc[2][3] = fmaf(a2, b.w, acc[2][3]);
        acc[3][0] = fmaf(a3, b.x, acc[3][0]);
        acc[3][1] = fmaf(a3, b.y, acc[3][1]);
        acc[3][2] = fmaf(a3, b.z, acc[3][2]);
        acc[3][3] = fmaf(a3, b.w, acc[3][3]);
    }

    float at[4], ab[4];
#pragma unroll
    for (int i = 0; i < 4; i++) {
        at[i] = a[c0 + i];
        ab[i] = a[OUT_F + c0 + i];
    }

#pragma unroll
    for (int ri = 0; ri < 4; ++ri) {
        int r = row0 + rl0 + ri;
        float ps = 0.0f, pt = 0.0f;
#pragma unroll
        for (int ci = 0; ci < 4; ++ci) {
            ps = fmaf(acc[ri][ci], at[ci], ps);
            pt = fmaf(acc[ri][ci], ab[ci], pt);
        }
#pragma unroll
        for (int o = 1; o < 16; o <<= 1) {
            ps += __shfl_xor(ps, o, 64);
            pt += __shfl_xor(pt, o, 64);
        }
        if (r < N_NODES) {
            *reinterpret_cast<float4*>(Wh + (size_t)r * OUT_F + c0) =
                make_float4(acc[ri][0], acc[ri][1], acc[ri][2], acc[ri][3]);
            if (tx == 0) { sv[r] = ps; tv[r] = pt; }
        }
    }
}

// --- counting sort by src: node-level histogram ---
__global__ void k_zero_i(int* __restrict__ p, int n) {
    int i = blockIdx.x * 256 + threadIdx.x;
    if (i < n) p[i] = 0;
}

__global__ void k_hist(const int* __restrict__ src, int* __restrict__ cnt) {
    int j = blockIdx.x * 256 + threadIdx.x;
    if (j < N_EDGES) atomicAdd(&cnt[src[j]], 1);
}

// hierarchical exclusive scan
__global__ __launch_bounds__(256) void k_scan1(const int* __restrict__ cnt,
                                               int* __restrict__ off,
                                               int* __restrict__ bsum) {
    __shared__ int s[256];
    int t = threadIdx.x;
    int i = blockIdx.x * 256 + t;
    int c = (i < N_NODES) ? cnt[i] : 0;
    s[t] = c;
    __syncthreads();
#pragma unroll
    for (int o = 1; o < 256; o <<= 1) {
        int v = (t >= o) ? s[t - o] : 0;
        __syncthreads();
        s[t] += v;
        __syncthreads();
    }
    if (i < N_NODES) off[i] = s[t] - c;
    if (t == 255) bsum[blockIdx.x] = s[255];
}

__global__ __launch_bounds__(256) void k_scan2(const int* __restrict__ bsum, int nb,
                                               int* __restrict__ boff) {
    __shared__ int s[256];
    int t = threadIdx.x;
    int c = (t < nb) ? bsum[t] : 0;
    s[t] = c;
    __syncthreads();
#pragma unroll
    for (int o = 1; o < 256; o <<= 1) {
        int v = (t >= o) ? s[t - o] : 0;
        __syncthreads();
        s[t] += v;
        __syncthreads();
    }
    if (t < nb) boff[t] = s[t] - c;
}

// finalize off; init padded per-bucket append counters (one per 64B line)
__global__ __launch_bounds__(256) void k_scan3(int* __restrict__ off,
                                               const int* __restrict__ boff,
                                               int* __restrict__ bheadg) {
    int i = blockIdx.x * 256 + threadIdx.x;
    if (i < N_NODES) {
        int v = off[i] + boff[blockIdx.x];
        off[i] = v;
        if ((i & (NPB - 1)) == 0) bheadg[(i / NPB) * 16] = v;
    }
    if (i == 0) off[N_NODES] = N_EDGES;
}

// Pass A: bucket-append scatter + edge score + online-softmax block stats.
// tmp[pos] = { d | (s&31)<<16 , bits(v) }, pos from per-bucket padded atomic.
__global__ __launch_bounds__(256) void k_bucket(const int* __restrict__ src,
                                                const int* __restrict__ dst,
                                                const float* __restrict__ sv,
                                                const float* __restrict__ tv,
                                                int* __restrict__ bheadg,
                                                int2* __restrict__ tmp,
                                                float* __restrict__ pmax,
                                                float* __restrict__ psum) {
    int j = blockIdx.x * 256 + threadIdx.x;
    float v = -INFINITY;
    if (j < N_EDGES) {
        int s = src[j], d = dst[j];
        v = sv[s] + tv[d];
        v = v > 0.0f ? v : LRELU_ALPHA * v;
        int pos = atomicAdd(&bheadg[(s / NPB) * 16], 1);
        tmp[pos] = make_int2(d | ((s & (NPB - 1)) << 16), __float_as_int(v));
    }
    // per-wave online softmax stats
    float wm = wred_max(v);
    wm = __shfl(wm, 0, 64);
    float ev = (j < N_EDGES) ? expf(v - wm) : 0.0f;
    float wsum = wred_sum(ev);

    __shared__ float rmx[4], rsm[4];
    if ((threadIdx.x & 63) == 0) {
        rmx[threadIdx.x >> 6] = wm;
        rsm[threadIdx.x >> 6] = wsum;
    }
    __syncthreads();
    if (threadIdx.x == 0) {
        float bm = fmaxf(fmaxf(rmx[0], rmx[1]), fmaxf(rmx[2], rmx[3]));
        float bs = 0.0f;
#pragma unroll
        for (int i = 0; i < 4; i++) bs += rsm[i] * expf(rmx[i] - bm);
        pmax[blockIdx.x] = bm;
        psum[blockIdx.x] = bs;
    }
}

// combine block stats: g[0]=gmax, g[1]=1/sum
__global__ __launch_bounds__(1024) void k_rcombine(const float* __restrict__ pmax,
                                                   const float* __restrict__ psum,
                                                   int n, float* __restrict__ g) {
    __shared__ float red[16];
    __shared__ float gm_s;
    int t = threadIdx.x;
    float lmax = -INFINITY;
    for (int i = t; i < n; i += 1024) lmax = fmaxf(lmax, pmax[i]);
    float wm = wred_max(lmax);
    if ((t & 63) == 0) red[t >> 6] = wm;
    __syncthreads();
    if (t == 0) {
        float m = red[0];
        for (int i = 1; i < 16; i++) m = fmaxf(m, red[i]);
        gm_s = m;
    }
    __syncthreads();
    float gm = gm_s;
    float lsum = 0.0f;
    for (int i = t; i < n; i += 1024) lsum += psum[i] * expf(pmax[i] - gm);
    float ws = wred_sum(lsum);
    __syncthreads();
    if ((t & 63) == 0) red[t >> 6] = ws;
    __syncthreads();
    if (t == 0) {
        float s = 0.0f;
        for (int i = 0; i < 16; i++) s += red[i];
        g[0] = gm;
        g[1] = 1.0f / s;
    }
}

// Fused sort+gather: one block per bucket. Chunked LDS counting-sort by
// local node id, then wave w accumulates nodes w*8..w*8+7 (lane = feature).
__global__ __launch_bounds__(256) void k_fgather(const int* __restrict__ off,
                                                 const int2* __restrict__ tmp,
                                                 const float* __restrict__ g,
                                                 const float* __restrict__ Wh,
                                                 float* __restrict__ out) {
    __shared__ int2 raw[CAP];
    __shared__ int2 sorted[CAP];
    __shared__ int scnt[NPB], soff[NPB], shead[NPB];

    const int b = blockIdx.x;
    const int tid = threadIdx.x;
    const int lane = tid & 63, w = tid >> 6;
    const float gm = g[0], ginv = g[1];

    const int n0 = b * NPB;
    int endn = n0 + NPB;
    if (endn > N_NODES) endn = N_NODES;
    int base = off[n0];
    const int end = off[endn];

    float acc[8];
#pragma unroll
    for (int i = 0; i < 8; i++) acc[i] = 0.0f;

    for (; base < end; base += CAP) {
        int cnt = end - base;
        if (cnt > CAP) cnt = CAP;

        for (int k = tid; k < cnt; k += 256) raw[k] = tmp[base + k];
        if (tid < NPB) scnt[tid] = 0;
        __syncthreads();

        for (int k = tid; k < cnt; k += 256)
            atomicAdd(&scnt[(raw[k].x >> 16) & (NPB - 1)], 1);
        __syncthreads();

        if (tid == 0) {
            int r = 0;
#pragma unroll
            for (int i = 0; i < NPB; i++) {
                soff[i] = r;
                shead[i] = r;
                r += scnt[i];
            }
        }
        __syncthreads();

        for (int k = tid; k < cnt; k += 256) {
            int2 e = raw[k];
            int sp = (e.x >> 16) & (NPB - 1);
            int r = atomicAdd(&shead[sp], 1);
            sorted[r] = make_int2(e.x & 0xFFFF, e.y);
        }
        __syncthreads();

#pragma unroll
        for (int i = 0; i < 8; i++) {
            int sp = w * 8 + i;
            int lo = soff[sp], c = scnt[sp];
            float a = acc[i];
            int t = 0;
            for (; t + 1 < c; t += 2) {
                int2 e0 = sorted[lo + t];
                int2 e1 = sorted[lo + t + 1];
                float w0 = Wh[(size_t)e0.x * OUT_F + lane];
                float w1 = Wh[(size_t)e1.x * OUT_F + lane];
                float a0 = expf(__int_as_float(e0.y) - gm);
                float a1 = expf(__int_as_float(e1.y) - gm);
                a = fmaf(a0, w0, a);
                a = fmaf(a1, w1, a);
            }
            if (t < c) {
                int2 e0 = sorted[lo + t];
                a = fmaf(expf(__int_as_float(e0.y) - gm),
                         Wh[(size_t)e0.x * OUT_F + lane], a);
            }
            acc[i] = a;
        }
        __syncthreads();
    }

#pragma unroll
    for (int i = 0; i < 8; i++) {
        int n = n0 + w * 8 + i;
        if (n < N_NODES) {
            float vv = acc[i] * ginv;
            out[(size_t)n * OUT_F + lane] = vv > 0.0f ? vv : expm1f(vv);
        }
    }
}

extern "C" void kernel_launch(void* const* d_in, const int* in_sizes, int n_in,
                              void* d_out, int out_size, void* d_ws, size_t ws_size,
                              hipStream_t stream) {
    const float* x  = (const float*)d_in[0];
    const int*   ei = (const int*)d_in[1];
    const float* W  = (const float*)d_in[2];
    const float* a  = (const float*)d_in[3];
    float* out = (float*)d_out;

    const int* src = ei;            // edge_index[0]
    const int* dst = ei + N_EDGES;  // edge_index[1]

    float* ws     = (float*)d_ws;
    float* Wh     = ws;                               // 3,200,000 f
    float* sv     = Wh + (size_t)N_NODES * OUT_F;     // 50,000 f
    float* tv     = sv + N_NODES;                     // 50,000 f
    float* pmax   = tv + N_NODES;                     // 4,096 f
    float* psum   = pmax + 4096;                      // 4,096 f
    float* g      = psum + 4096;                      // 2 f (gmax, ginv)
    int*   cnt    = (int*)(g + 2);                    // 50,000 i
    int*   off    = cnt + N_NODES;                    // 50,001 i
    int*   bsum   = off + N_NODES + 1;                // 256 i
    int*   boff   = bsum + 256;                       // 256 i
    int*   bheadg = boff + 256;                       // NBUCK*16 i (padded)
    // 16B-align tmp
    size_t used = (size_t)((char*)(bheadg + NBUCK * 16) - (char*)d_ws);
    used = (used + 15) & ~(size_t)15;
    int2*  tmp  = (int2*)((char*)d_ws + used);        // 800,000 int2 = 6.4 MB

    const int NBN = (N_NODES + 255) / 256;   // 196
    const int NBE = (N_EDGES + 255) / 256;   // 3125

    k_zero_i<<<NBN, 256, 0, stream>>>(cnt, N_NODES);
    k_wh<<<(N_NODES + 63) / 64, 256, 0, stream>>>(x, W, a, Wh, sv, tv);
    k_hist<<<NBE, 256, 0, stream>>>(src, cnt);
    k_scan1<<<NBN, 256, 0, stream>>>(cnt, off, bsum);
    k_scan2<<<1, 256, 0, stream>>>(bsum, NBN, boff);
    k_scan3<<<NBN, 256, 0, stream>>>(off, boff, bheadg);
    k_bucket<<<NBE, 256, 0, stream>>>(src, dst, sv, tv, bheadg, tmp, pmax, psum);
    k_rcombine<<<1, 1024, 0, stream>>>(pmax, psum, NBE, g);
    k_fgather<<<NBUCK, 256, 0, stream>>>(off, tmp, g, Wh, out);
}

// Round 7
// 167.765 us; speedup vs baseline: 1.0264x; 1.0264x over previous
//
#include <hip/hip_runtime.h>
#include <math.h>

#define N_NODES 50000
#define N_EDGES 800000
#define IN_F 128
#define OUT_F 64
#define LRELU_ALPHA 0.2f

__device__ inline float wred_max(float v) {
#pragma unroll
    for (int o = 32; o > 0; o >>= 1) v = fmaxf(v, __shfl_down(v, o, 64));
    return v;
}
__device__ inline float wred_sum(float v) {
#pragma unroll
    for (int o = 32; o > 0; o >>= 1) v += __shfl_down(v, o, 64);
    return v;
}

// K1: Wh = x @ W, register-tiled: 64x64 tile per block, 4x4 per thread.
__global__ __launch_bounds__(256, 2) void k_wh(const float* __restrict__ x,
                                               const float* __restrict__ W,
                                               const float* __restrict__ a,
                                               float* __restrict__ Wh,
                                               float* __restrict__ sv,
                                               float* __restrict__ tv) {
    __shared__ float xs[64 * 128];  // x tile, XOR-swizzled
    __shared__ float Ws[128 * 64];  // W, natural layout

    const int tid = threadIdx.x;
    const int row0 = blockIdx.x * 64;

    for (int i = tid; i < 64 * 32; i += 256) {
        int rl = i >> 5, c4 = (i & 31) << 2;
        int r = row0 + rl;
        float4 v = make_float4(0.f, 0.f, 0.f, 0.f);
        if (r < N_NODES) v = *reinterpret_cast<const float4*>(x + (size_t)r * IN_F + c4);
        int sw = c4 ^ ((rl & 7) << 2);
        *reinterpret_cast<float4*>(&xs[rl * 128 + sw]) = v;
    }
    for (int i = tid; i < 128 * 16; i += 256) {
        int k = i >> 4, c4 = (i & 15) << 2;
        *reinterpret_cast<float4*>(&Ws[k * 64 + c4]) =
            *reinterpret_cast<const float4*>(W + k * 64 + c4);
    }
    __syncthreads();

    const int tx = tid & 15;
    const int ty = tid >> 4;
    const int c0 = tx << 2;
    const int rl0 = ty << 2;

    float acc[4][4] = {};
#pragma unroll 4
    for (int k = 0; k < 128; ++k) {
        float4 b = *reinterpret_cast<const float4*>(&Ws[k * 64 + c0]);
        float a0 = xs[(rl0 + 0) * 128 + (k ^ (((rl0 + 0) & 7) << 2))];
        float a1 = xs[(rl0 + 1) * 128 + (k ^ (((rl0 + 1) & 7) << 2))];
        float a2 = xs[(rl0 + 2) * 128 + (k ^ (((rl0 + 2) & 7) << 2))];
        float a3 = xs[(rl0 + 3) * 128 + (k ^ (((rl0 + 3) & 7) << 2))];
        acc[0][0] = fmaf(a0, b.x, acc[0][0]);
        acc[0][1] = fmaf(a0, b.y, acc[0][1]);
        acc[0][2] = fmaf(a0, b.z, acc[0][2]);
        acc[0][3] = fmaf(a0, b.w, acc[0][3]);
        acc[1][0] = fmaf(a1, b.x, acc[1][0]);
        acc[1][1] = fmaf(a1, b.y, acc[1][1]);
        acc[1][2] = fmaf(a1, b.z, acc[1][2]);
        acc[1][3] = fmaf(a1, b.w, acc[1][3]);
        acc[2][0] = fmaf(a2, b.x, acc[2][0]);
        acc[2][1] = fmaf(a2, b.y, acc[2][1]);
        acc[2][2] = fmaf(a2, b.z, acc[2][2]);
        acc[2][3] = fmaf(a2, b.w, acc[2][3]);
        acc[3][0] = fmaf(a3, b.x, acc[3][0]);
        acc[3][1] = fmaf(a3, b.y, acc[3][1]);
        acc[3][2] = fmaf(a3, b.z, acc[3][2]);
        acc[3][3] = fmaf(a3, b.w, acc[3][3]);
    }

    float at[4], ab[4];
#pragma unroll
    for (int i = 0; i < 4; i++) {
        at[i] = a[c0 + i];
        ab[i] = a[OUT_F + c0 + i];
    }

#pragma unroll
    for (int ri = 0; ri < 4; ++ri) {
        int r = row0 + rl0 + ri;
        float ps = 0.0f, pt = 0.0f;
#pragma unroll
        for (int ci = 0; ci < 4; ++ci) {
            ps = fmaf(acc[ri][ci], at[ci], ps);
            pt = fmaf(acc[ri][ci], ab[ci], pt);
        }
#pragma unroll
        for (int o = 1; o < 16; o <<= 1) {
            ps += __shfl_xor(ps, o, 64);
            pt += __shfl_xor(pt, o, 64);
        }
        if (r < N_NODES) {
            *reinterpret_cast<float4*>(Wh + (size_t)r * OUT_F + c0) =
                make_float4(acc[ri][0], acc[ri][1], acc[ri][2], acc[ri][3]);
            if (tx == 0) { sv[r] = ps; tv[r] = pt; }
        }
    }
}

// --- counting sort by src: histogram (4 edges/thread, int4 loads) ---
__global__ void k_zero_i(int* __restrict__ p, int n) {
    int i = blockIdx.x * 256 + threadIdx.x;
    if (i < n) p[i] = 0;
}

__global__ __launch_bounds__(256) void k_hist(const int* __restrict__ src,
                                              int* __restrict__ cnt) {
    int t = blockIdx.x * 256 + threadIdx.x;
    int j0 = t * 4;  // N_EDGES % 4 == 0
    if (j0 >= N_EDGES) return;
    int4 s4 = *reinterpret_cast<const int4*>(src + j0);
    atomicAdd(&cnt[s4.x], 1);
    atomicAdd(&cnt[s4.y], 1);
    atomicAdd(&cnt[s4.z], 1);
    atomicAdd(&cnt[s4.w], 1);
}

// hierarchical exclusive scan
__global__ __launch_bounds__(256) void k_scan1(const int* __restrict__ cnt,
                                               int* __restrict__ off,
                                               int* __restrict__ bsum) {
    __shared__ int s[256];
    int t = threadIdx.x;
    int i = blockIdx.x * 256 + t;
    int c = (i < N_NODES) ? cnt[i] : 0;
    s[t] = c;
    __syncthreads();
#pragma unroll
    for (int o = 1; o < 256; o <<= 1) {
        int v = (t >= o) ? s[t - o] : 0;
        __syncthreads();
        s[t] += v;
        __syncthreads();
    }
    if (i < N_NODES) off[i] = s[t] - c;
    if (t == 255) bsum[blockIdx.x] = s[255];
}

__global__ __launch_bounds__(256) void k_scan2(const int* __restrict__ bsum, int nb,
                                               int* __restrict__ boff) {
    __shared__ int s[256];
    int t = threadIdx.x;
    int c = (t < nb) ? bsum[t] : 0;
    s[t] = c;
    __syncthreads();
#pragma unroll
    for (int o = 1; o < 256; o <<= 1) {
        int v = (t >= o) ? s[t - o] : 0;
        __syncthreads();
        s[t] += v;
        __syncthreads();
    }
    if (t < nb) boff[t] = s[t] - c;
}

__global__ __launch_bounds__(256) void k_scan3(int* __restrict__ off,
                                               int* __restrict__ head,
                                               const int* __restrict__ boff) {
    int i = blockIdx.x * 256 + threadIdx.x;
    if (i < N_NODES) {
        int v = off[i] + boff[blockIdx.x];
        off[i] = v;
        head[i] = v;
    }
    if (i == 0) off[N_NODES] = N_EDGES;
}

// fused permutation + edge score + online-softmax block stats.
// 4 edges per thread: 4 independent gather/atomic/store chains in flight.
__global__ __launch_bounds__(256) void k_permedge(const int* __restrict__ src,
                                                  const int* __restrict__ dst,
                                                  const float* __restrict__ sv,
                                                  const float* __restrict__ tv,
                                                  int* __restrict__ head,
                                                  int2* __restrict__ rec,
                                                  float* __restrict__ pmax,
                                                  float* __restrict__ psum) {
    int t = blockIdx.x * 256 + threadIdx.x;
    int j0 = t * 4;  // N_EDGES % 4 == 0 -> thread is fully valid or fully invalid
    bool ok = (j0 < N_EDGES);

    float v[4];
    float lmax = -INFINITY;
    if (ok) {
        int4 s4 = *reinterpret_cast<const int4*>(src + j0);
        int4 d4 = *reinterpret_cast<const int4*>(dst + j0);
        int s_[4] = {s4.x, s4.y, s4.z, s4.w};
        int d_[4] = {d4.x, d4.y, d4.z, d4.w};
        // 4 independent rank atomics (issue first: nothing depends on them yet)
        int p_[4];
#pragma unroll
        for (int k = 0; k < 4; k++) p_[k] = atomicAdd(&head[s_[k]], 1);
        // 8 independent scalar gathers
        float svv[4], tvv[4];
#pragma unroll
        for (int k = 0; k < 4; k++) svv[k] = sv[s_[k]];
#pragma unroll
        for (int k = 0; k < 4; k++) tvv[k] = tv[d_[k]];
#pragma unroll
        for (int k = 0; k < 4; k++) {
            float vv = svv[k] + tvv[k];
            vv = vv > 0.0f ? vv : LRELU_ALPHA * vv;
            v[k] = vv;
            lmax = fmaxf(lmax, vv);
        }
        // 4 independent scattered stores
#pragma unroll
        for (int k = 0; k < 4; k++)
            rec[p_[k]] = make_int2(d_[k], __float_as_int(v[k]));
    }

    // per-wave online softmax stats over the 1024 edges this block owns
    float wm = wred_max(lmax);
    wm = __shfl(wm, 0, 64);
    float ev = 0.0f;
    if (ok) {
#pragma unroll
        for (int k = 0; k < 4; k++) ev += expf(v[k] - wm);
    }
    float wsum = wred_sum(ev);

    __shared__ float rmx[4], rsm[4];
    if ((threadIdx.x & 63) == 0) {
        rmx[threadIdx.x >> 6] = wm;
        rsm[threadIdx.x >> 6] = wsum;
    }
    __syncthreads();
    if (threadIdx.x == 0) {
        float bm = fmaxf(fmaxf(rmx[0], rmx[1]), fmaxf(rmx[2], rmx[3]));
        float bs = 0.0f;
#pragma unroll
        for (int i = 0; i < 4; i++)
            bs += (rmx[i] == -INFINITY) ? 0.0f : rsm[i] * expf(rmx[i] - bm);
        pmax[blockIdx.x] = bm;
        psum[blockIdx.x] = bs;
    }
}

// combine block stats: g[0]=gmax, g[1]=1/sum
__global__ __launch_bounds__(1024) void k_rcombine(const float* __restrict__ pmax,
                                                   const float* __restrict__ psum,
                                                   int n, float* __restrict__ g) {
    __shared__ float red[16];
    __shared__ float gm_s;
    int t = threadIdx.x;
    float lmax = -INFINITY;
    for (int i = t; i < n; i += 1024) lmax = fmaxf(lmax, pmax[i]);
    float wm = wred_max(lmax);
    if ((t & 63) == 0) red[t >> 6] = wm;
    __syncthreads();
    if (t == 0) {
        float m = red[0];
        for (int i = 1; i < 16; i++) m = fmaxf(m, red[i]);
        gm_s = m;
    }
    __syncthreads();
    float gm = gm_s;
    float lsum = 0.0f;
    for (int i = t; i < n; i += 1024)
        lsum += (pmax[i] == -INFINITY) ? 0.0f : psum[i] * expf(pmax[i] - gm);
    float ws = wred_sum(lsum);
    __syncthreads();
    if ((t & 63) == 0) red[t >> 6] = ws;
    __syncthreads();
    if (t == 0) {
        float s = 0.0f;
        for (int i = 0; i < 16; i++) s += red[i];
        g[0] = gm;
        g[1] = 1.0f / s;
    }
}

// K4: per-node gather; exp applied inline; out = elu(ginv * sum p*Wh[d])
__global__ __launch_bounds__(256) void k_gather(const int* __restrict__ off,
                                                const int2* __restrict__ rec,
                                                const float* __restrict__ g,
                                                const float* __restrict__ Wh,
                                                float* __restrict__ out) {
    int n = blockIdx.x * 4 + (threadIdx.x >> 6);
    int f = threadIdx.x & 63;
    if (n >= N_NODES) return;
    float gm = g[0], ginv = g[1];
    int start = off[n], end = off[n + 1];
    float acc = 0.0f;
    for (int base = start; base < end; base += 64) {
        int cnt = end - base;
        if (cnt > 64) cnt = 64;
        int dj = 0;
        float att = 0.0f;
        if (f < cnt) {
            int2 r = rec[base + f];
            dj = r.x;
            att = expf(__int_as_float(r.y) - gm);
        }
        int i = 0;
        for (; i + 3 < cnt; i += 4) {
            int j0 = __shfl(dj, i, 64), j1 = __shfl(dj, i + 1, 64);
            int j2 = __shfl(dj, i + 2, 64), j3 = __shfl(dj, i + 3, 64);
            float a0 = __shfl(att, i, 64), a1 = __shfl(att, i + 1, 64);
            float a2 = __shfl(att, i + 2, 64), a3 = __shfl(att, i + 3, 64);
            float w0 = Wh[(size_t)j0 * OUT_F + f];
            float w1 = Wh[(size_t)j1 * OUT_F + f];
            float w2 = Wh[(size_t)j2 * OUT_F + f];
            float w3 = Wh[(size_t)j3 * OUT_F + f];
            acc = fmaf(a0, w0, acc);
            acc = fmaf(a1, w1, acc);
            acc = fmaf(a2, w2, acc);
            acc = fmaf(a3, w3, acc);
        }
        for (; i < cnt; i++) {
            int jj = __shfl(dj, i, 64);
            float aa = __shfl(att, i, 64);
            acc = fmaf(aa, Wh[(size_t)jj * OUT_F + f], acc);
        }
    }
    acc *= ginv;
    out[(size_t)n * OUT_F + f] = acc > 0.0f ? acc : expm1f(acc);
}

extern "C" void kernel_launch(void* const* d_in, const int* in_sizes, int n_in,
                              void* d_out, int out_size, void* d_ws, size_t ws_size,
                              hipStream_t stream) {
    const float* x  = (const float*)d_in[0];
    const int*   ei = (const int*)d_in[1];
    const float* W  = (const float*)d_in[2];
    const float* a  = (const float*)d_in[3];
    float* out = (float*)d_out;

    const int* src = ei;            // edge_index[0]
    const int* dst = ei + N_EDGES;  // edge_index[1]

    float* ws   = (float*)d_ws;
    float* Wh   = ws;                               // 3,200,000 f
    float* sv   = Wh + (size_t)N_NODES * OUT_F;     // 50,000 f
    float* tv   = sv + N_NODES;                     // 50,000 f
    float* pmax = tv + N_NODES;                     // 4,096 f
    float* psum = pmax + 4096;                      // 4,096 f
    float* g    = psum + 4096;                      // 2 f (gmax, ginv)
    int*   cnt  = (int*)(g + 2);                    // 50,000 i
    int*   off  = cnt + N_NODES;                    // 50,001 i
    int*   head = off + N_NODES + 1;                // 50,000 i
    int*   bsum = head + N_NODES;                   // 256 i
    int*   boff = bsum + 256;                       // 256 i
    // 16B-align rec
    size_t used = (size_t)((char*)(boff + 256) - (char*)d_ws);
    used = (used + 15) & ~(size_t)15;
    int2*  rec  = (int2*)((char*)d_ws + used);      // 800,000 int2 = 6.4 MB

    const int NBN = (N_NODES + 255) / 256;           // 196
    const int NBT = (N_EDGES / 4 + 255) / 256;       // 782 (4 edges/thread)

    k_zero_i<<<NBN, 256, 0, stream>>>(cnt, N_NODES);
    k_wh<<<(N_NODES + 63) / 64, 256, 0, stream>>>(x, W, a, Wh, sv, tv);
    k_hist<<<NBT, 256, 0, stream>>>(src, cnt);
    k_scan1<<<NBN, 256, 0, stream>>>(cnt, off, bsum);
    k_scan2<<<1, 256, 0, stream>>>(bsum, NBN, boff);
    k_scan3<<<NBN, 256, 0, stream>>>(off, head, boff);
    k_permedge<<<NBT, 256, 0, stream>>>(src, dst, sv, tv, head, rec, pmax, psum);
    k_rcombine<<<1, 1024, 0, stream>>>(pmax, psum, NBT, g);
    k_gather<<<(N_NODES + 3) / 4, 256, 0, stream>>>(off, rec, g, Wh, out);
}